// Round 5
// baseline (428.417 us; speedup 1.0000x reference)
//
#include <hip/hip_runtime.h>

typedef _Float16 f16x8 __attribute__((ext_vector_type(8)));
typedef _Float16 f16x4 __attribute__((ext_vector_type(4)));
typedef float f32x4 __attribute__((ext_vector_type(4)));
typedef float f32x16 __attribute__((ext_vector_type(16)));

#define BN_EPS 1e-5f
#define SQRT32 5.656854249492381f
#define LOG2E  1.4426950408889634f

// ---------------------------------------------------------------- prep (merged)
// z<16: x [b][c=384][n] fp32 -> xT_hi/lo [b][n][c] fp16 planes (transpose+split).
// z==16: weight conversion + BN affine fold.
__global__ __launch_bounds__(256) void prep(
    const float* __restrict__ x,
    const float* __restrict__ wq, const float* __restrict__ wk,
    const float* __restrict__ wv, const float* __restrict__ wp,
    const float* __restrict__ bnq, const float* __restrict__ bnk,
    const float* __restrict__ bnv, const float* __restrict__ bnp,
    _Float16* __restrict__ xT_hi, _Float16* __restrict__ xT_lo,
    _Float16* __restrict__ wqk_h, _Float16* __restrict__ wqk_l,
    _Float16* __restrict__ wv_h,  _Float16* __restrict__ wp_h,
    float* __restrict__ s_qkv, float* __restrict__ t_qkv,
    float* __restrict__ s_p,   float* __restrict__ t_p)
{
    __shared__ float Tx[64][65];
    const int t = threadIdx.x;
    if (blockIdx.z < 16) {
        const int ct = blockIdx.x, nt = blockIdx.y, b = blockIdx.z;
        const int c0 = ct * 64, n0 = nt * 64;
        {
            int tr = t >> 4, tc = (t & 15) * 4;
            #pragma unroll
            for (int p = 0; p < 4; p++) {
                int r = tr + p * 16;
                float4 v = *(const float4*)(x + ((size_t)(b * 384 + c0 + r)) * 1024 + n0 + tc);
                Tx[r][tc + 0] = v.x; Tx[r][tc + 1] = v.y; Tx[r][tc + 2] = v.z; Tx[r][tc + 3] = v.w;
            }
        }
        __syncthreads();
        {
            int nn = t >> 2, cc = (t & 3) * 16;
            f16x8 h0, h1, l0, l1;
            #pragma unroll
            for (int i = 0; i < 8; i++) {
                float v = Tx[cc + i][nn];
                _Float16 hh = (_Float16)v;
                h0[i] = hh; l0[i] = (_Float16)(v - (float)hh);
            }
            #pragma unroll
            for (int i = 0; i < 8; i++) {
                float v = Tx[cc + 8 + i][nn];
                _Float16 hh = (_Float16)v;
                h1[i] = hh; l1[i] = (_Float16)(v - (float)hh);
            }
            size_t o = ((size_t)(b * 1024 + n0 + nn)) * 384 + c0 + cc;
            *(f16x8*)(xT_hi + o) = h0; *(f16x8*)(xT_hi + o + 8) = h1;
            *(f16x8*)(xT_lo + o) = l0; *(f16x8*)(xT_lo + o + 8) = l1;
        }
    } else {
        const int NQK = 512 * 384, NV = 1024 * 384, NP = 384 * 1024;
        int tid = (blockIdx.y * 6 + blockIdx.x) * 256 + t;       // 0..24575
        for (int i = tid; i < NQK + NV + NP; i += 24576) {
            if (i < NQK) {
                int o = i / 384, c = i - o * 384;
                float v = (o < 256) ? wq[o * 384 + c] : wk[(o - 256) * 384 + c];
                _Float16 hh = (_Float16)v;
                wqk_h[i] = hh; wqk_l[i] = (_Float16)(v - (float)hh);
            } else if (i < NQK + NV) {
                wv_h[i - NQK] = (_Float16)wv[i - NQK];
            } else {
                wp_h[i - NQK - NV] = (_Float16)wp[i - NQK - NV];
            }
        }
        if (tid < 1536) {
            int i = tid;
            float g, be, m, v;
            if (i < 256)      { int o = i;       g = bnq[o]; be = bnq[256 + o];  m = bnq[512 + o];  v = bnq[768 + o]; }
            else if (i < 512) { int o = i - 256; g = bnk[o]; be = bnk[256 + o];  m = bnk[512 + o];  v = bnk[768 + o]; }
            else              { int o = i - 512; g = bnv[o]; be = bnv[1024 + o]; m = bnv[2048 + o]; v = bnv[3072 + o]; }
            float s = g * rsqrtf(v + BN_EPS);
            float tt = be - m * s;
            // fold /scale (= *sqrt(kd)) AND log2(e) (exp2 softmax) into Q's affine
            if (i < 256) { s *= SQRT32 * LOG2E; tt *= SQRT32 * LOG2E; }
            s_qkv[i] = s; t_qkv[i] = tt;
        } else if (tid < 1536 + 384) {
            int o = tid - 1536;
            float g = bnp[o], be = bnp[384 + o], m = bnp[768 + o], v = bnp[1152 + o];
            float s = g * rsqrtf(v + BN_EPS);
            s_p[o] = s; t_p[o] = be - m * s;
        }
    }
}

// ---------------------------------------------------------------- gemm_qkv
// bx<4 (Q/K rows): computes D[n][o] (transposed, 3-term hi/lo) and writes
// qT/kT [b][h][n][32] hi/lo fp16 planes directly.
// bx>=4 (V rows): D[o][n] 1-term, fp16 out, natural layout.
__global__ __launch_bounds__(256, 2) void gemm_qkv(
    const _Float16* __restrict__ wqk_h, const _Float16* __restrict__ wqk_l,
    const _Float16* __restrict__ wv_h,
    const _Float16* __restrict__ xT_hi, const _Float16* __restrict__ xT_lo,
    const float* __restrict__ S, const float* __restrict__ T,
    _Float16* __restrict__ qT_h, _Float16* __restrict__ qT_l,
    _Float16* __restrict__ kT_h, _Float16* __restrict__ kT_l,
    _Float16* __restrict__ vbuf)
{
    __shared__ __align__(16) _Float16 As_h[128 * 40];
    __shared__ __align__(16) _Float16 As_l[128 * 40];
    __shared__ __align__(16) _Float16 Bs_h[128 * 40];
    __shared__ __align__(16) _Float16 Bs_l[128 * 40];
    const int t = threadIdx.x, lane = t & 63, w = t >> 6;
    const int wr = w >> 1, wc = w & 1, l16 = lane & 15, lq = lane >> 4;
    const int bx = blockIdx.x, n0 = blockIdx.y * 128, b = blockIdx.z;
    const bool isv = bx >= 4;
    const int o0 = isv ? (bx - 4) * 128 : bx * 128;
    const _Float16* __restrict__ Ah = isv ? wv_h : wqk_h;

    f32x4 acc[4][4] = {};

    for (int kb = 0; kb < 384; kb += 32) {
        __syncthreads();
        #pragma unroll
        for (int p = 0; p < 2; p++) {
            int g = t + p * 256, row = g >> 2, ch = g & 3;
            *(uint4*)(&As_h[row * 40 + ch * 8]) =
                *(const uint4*)(Ah + (size_t)(o0 + row) * 384 + kb + ch * 8);
        }
        #pragma unroll
        for (int p = 0; p < 2; p++) {
            int g = t + p * 256, row = g >> 2, ch = g & 3;
            *(uint4*)(&Bs_h[row * 40 + ch * 8]) =
                *(const uint4*)(xT_hi + ((size_t)(b * 1024) + n0 + row) * 384 + kb + ch * 8);
        }
        if (!isv) {
            #pragma unroll
            for (int p = 0; p < 2; p++) {
                int g = t + p * 256, row = g >> 2, ch = g & 3;
                *(uint4*)(&As_l[row * 40 + ch * 8]) =
                    *(const uint4*)(wqk_l + (size_t)(o0 + row) * 384 + kb + ch * 8);
            }
            #pragma unroll
            for (int p = 0; p < 2; p++) {
                int g = t + p * 256, row = g >> 2, ch = g & 3;
                *(uint4*)(&Bs_l[row * 40 + ch * 8]) =
                    *(const uint4*)(xT_lo + ((size_t)(b * 1024) + n0 + row) * 384 + kb + ch * 8);
            }
        }
        __syncthreads();

        if (!isv) {
            // transposed: A = x tiles (n rows), B = w tiles (o cols)
            f16x8 ah[4], al[4], bh[4], bl[4];
            #pragma unroll
            for (int i = 0; i < 4; i++) {
                ah[i] = *(const f16x8*)(&Bs_h[(wr * 64 + i * 16 + l16) * 40 + lq * 8]);
                al[i] = *(const f16x8*)(&Bs_l[(wr * 64 + i * 16 + l16) * 40 + lq * 8]);
            }
            #pragma unroll
            for (int j = 0; j < 4; j++) {
                bh[j] = *(const f16x8*)(&As_h[(wc * 64 + j * 16 + l16) * 40 + lq * 8]);
                bl[j] = *(const f16x8*)(&As_l[(wc * 64 + j * 16 + l16) * 40 + lq * 8]);
            }
            #pragma unroll
            for (int i = 0; i < 4; i++)
                #pragma unroll
                for (int j = 0; j < 4; j++) {
                    acc[i][j] = __builtin_amdgcn_mfma_f32_16x16x32_f16(ah[i], bh[j], acc[i][j], 0, 0, 0);
                    acc[i][j] = __builtin_amdgcn_mfma_f32_16x16x32_f16(al[i], bh[j], acc[i][j], 0, 0, 0);
                    acc[i][j] = __builtin_amdgcn_mfma_f32_16x16x32_f16(ah[i], bl[j], acc[i][j], 0, 0, 0);
                }
        } else {
            f16x8 a[4], bf[4];
            #pragma unroll
            for (int i = 0; i < 4; i++) a[i]  = *(const f16x8*)(&As_h[(wr * 64 + i * 16 + l16) * 40 + lq * 8]);
            #pragma unroll
            for (int j = 0; j < 4; j++) bf[j] = *(const f16x8*)(&Bs_h[(wc * 64 + j * 16 + l16) * 40 + lq * 8]);
            #pragma unroll
            for (int i = 0; i < 4; i++)
                #pragma unroll
                for (int j = 0; j < 4; j++)
                    acc[i][j] = __builtin_amdgcn_mfma_f32_16x16x32_f16(a[i], bf[j], acc[i][j], 0, 0, 0);
        }
    }

    if (!isv) {
        // D[n][o]: row = n, col(l16) = o. Write qT/kT hi/lo planes directly.
        #pragma unroll
        for (int i = 0; i < 4; i++) {
            #pragma unroll
            for (int r = 0; r < 4; r++) {
                int n = n0 + wr * 64 + i * 16 + lq * 4 + r;
                #pragma unroll
                for (int j = 0; j < 4; j++) {
                    int o = o0 + wc * 64 + j * 16 + l16;
                    float sc = S[o], sh = T[o];
                    float v = acc[i][j][r] * sc + sh;
                    _Float16 hh = (_Float16)v;
                    _Float16 ll = (_Float16)(v - (float)hh);
                    int oo = o & 255;
                    size_t idx = (((size_t)(b * 8) + (oo >> 5)) * 1024 + n) * 32 + (oo & 31);
                    if (o < 256) { qT_h[idx] = hh; qT_l[idx] = ll; }
                    else         { kT_h[idx] = hh; kT_l[idx] = ll; }
                }
            }
        }
    } else {
        #pragma unroll
        for (int i = 0; i < 4; i++) {
            #pragma unroll
            for (int r = 0; r < 4; r++) {
                int o = o0 + wr * 64 + i * 16 + lq * 4 + r;
                float sc = S[512 + o], sh = T[512 + o];
                #pragma unroll
                for (int j = 0; j < 4; j++) {
                    int n = n0 + wc * 64 + j * 16 + l16;
                    vbuf[((size_t)(b * 1024) + o) * 1024 + n] = (_Float16)(acc[i][j][r] * sc + sh);
                }
            }
        }
    }
}

// ---------------------------------------------------------------- attn
// Two-pass exact-max flash attention. 512 thr = 8 waves, 512 q/block,
// grid (bh=128, qt=2) = 256 blocks. Scores transposed D[key][q] (A=K, B=Q).
// Pass A: exact per-q max; K read from global (L2-hot), NO LDS, NO barriers.
// Pass B: identical QK MFMA sequence, P = exp2(s-m) (no max reduce, no alpha,
// no o rescale), l as per-lane partials (1 shuffle at end). V double-buffered
// in LDS with register prefetch, 1 barrier/iter. PV via mfma 32x32x8 (P regs
// map directly onto B-operand, zero repack).
__device__ __forceinline__ f32x16 qk6(f16x8 kh0, f16x8 kl0, f16x8 kh1, f16x8 kl1,
                                      f16x8 qh0, f16x8 ql0, f16x8 qh1, f16x8 ql1) {
    f32x16 c = {};
    c = __builtin_amdgcn_mfma_f32_32x32x16_f16(kh0, qh0, c, 0, 0, 0);
    c = __builtin_amdgcn_mfma_f32_32x32x16_f16(kl0, qh0, c, 0, 0, 0);
    c = __builtin_amdgcn_mfma_f32_32x32x16_f16(kh0, ql0, c, 0, 0, 0);
    c = __builtin_amdgcn_mfma_f32_32x32x16_f16(kh1, qh1, c, 0, 0, 0);
    c = __builtin_amdgcn_mfma_f32_32x32x16_f16(kl1, qh1, c, 0, 0, 0);
    c = __builtin_amdgcn_mfma_f32_32x32x16_f16(kh1, ql1, c, 0, 0, 0);
    return c;
}

__global__ __launch_bounds__(512, 2) void attn(
    const _Float16* __restrict__ qT_h, const _Float16* __restrict__ qT_l,
    const _Float16* __restrict__ kT_h, const _Float16* __restrict__ kT_l,
    const _Float16* __restrict__ vbuf,
    _Float16* __restrict__ xxT_h, _Float16* __restrict__ xxT_l)
{
    __shared__ __align__(16) _Float16 Vs[2][128 * 72];
    const int t = threadIdx.x, lane = t & 63, w = t >> 6;
    const int L = lane & 31, hl = lane >> 5;
    const int bh = blockIdx.x, qt = blockIdx.y;
    const int b = bh >> 3, h = bh & 7;

    // Q B-frags (hi/lo planes, direct f16 loads)
    f16x8 bq_h[2][2], bq_l[2][2];
    #pragma unroll
    for (int g = 0; g < 2; g++) {
        int q = qt * 512 + w * 64 + g * 32 + L;
        #pragma unroll
        for (int kh = 0; kh < 2; kh++) {
            size_t base = ((size_t)(bh * 1024) + q) * 32 + kh * 16 + hl * 8;
            bq_h[g][kh] = *(const f16x8*)(qT_h + base);
            bq_l[g][kh] = *(const f16x8*)(qT_l + base);
        }
    }

    // ---- pass A: exact max (no LDS, no barriers)
    float m0 = -INFINITY, m1 = -INFINITY;
    for (int kt = 0; kt < 16; kt++) {
        #pragma unroll
        for (int sub = 0; sub < 2; sub++) {
            size_t kb = ((size_t)(bh * 1024) + kt * 64 + sub * 32 + L) * 32 + hl * 8;
            f16x8 kh0 = *(const f16x8*)(kT_h + kb);
            f16x8 kl0 = *(const f16x8*)(kT_l + kb);
            f16x8 kh1 = *(const f16x8*)(kT_h + kb + 16);
            f16x8 kl1 = *(const f16x8*)(kT_l + kb + 16);
            f32x16 c0 = qk6(kh0, kl0, kh1, kl1, bq_h[0][0], bq_l[0][0], bq_h[0][1], bq_l[0][1]);
            #pragma unroll
            for (int i = 0; i < 16; i++) m0 = fmaxf(m0, c0[i]);
            f32x16 c1 = qk6(kh0, kl0, kh1, kl1, bq_h[1][0], bq_l[1][0], bq_h[1][1], bq_l[1][1]);
            #pragma unroll
            for (int i = 0; i < 16; i++) m1 = fmaxf(m1, c1[i]);
        }
    }
    m0 = fmaxf(m0, __shfl_xor(m0, 32, 64));
    m1 = fmaxf(m1, __shfl_xor(m1, 32, 64));
    const float m[2] = {m0, m1};

    // ---- pass B
    f32x16 o_acc[2][4] = {};
    float lsum[2] = {0.f, 0.f};

    // stage V tile 0 into Vs[0] (granule-rotated, conflict-free reads)
    #pragma unroll
    for (int p = 0; p < 2; p++) {
        int g2 = t + p * 512, d = g2 >> 3, kc = g2 & 7;
        int kc2 = (kc + (d >> 3)) & 7;
        *(uint4*)(&Vs[0][d * 72 + kc2 * 8]) =
            *(const uint4*)(vbuf + ((size_t)(b * 1024) + h * 128 + d) * 1024 + kc * 8);
    }
    __syncthreads();

    for (int kt = 0; kt < 16; kt++) {
        const int cur = kt & 1;
        // prefetch V tile kt+1 into regs (overlaps compute)
        uint4 vx0, vx1;
        if (kt < 15) {
            #pragma unroll
            for (int p = 0; p < 2; p++) {
                int g2 = t + p * 512, d = g2 >> 3, kc = g2 & 7;
                uint4 v = *(const uint4*)(vbuf + ((size_t)(b * 1024) + h * 128 + d) * 1024 + (kt + 1) * 64 + kc * 8);
                if (p == 0) vx0 = v; else vx1 = v;
            }
        }

        // QK (identical sequence to pass A) -> P = exp2(s - m)
        f16x4 pfrag[2][8];
        #pragma unroll
        for (int sub = 0; sub < 2; sub++) {
            size_t kb = ((size_t)(bh * 1024) + kt * 64 + sub * 32 + L) * 32 + hl * 8;
            f16x8 kh0 = *(const f16x8*)(kT_h + kb);
            f16x8 kl0 = *(const f16x8*)(kT_l + kb);
            f16x8 kh1 = *(const f16x8*)(kT_h + kb + 16);
            f16x8 kl1 = *(const f16x8*)(kT_l + kb + 16);
            #pragma unroll
            for (int g = 0; g < 2; g++) {
                f32x16 c = qk6(kh0, kl0, kh1, kl1, bq_h[g][0], bq_l[g][0], bq_h[g][1], bq_l[g][1]);
                float rs0 = 0.f, rs1 = 0.f;
                #pragma unroll
                for (int qq = 0; qq < 4; qq++) {
                    #pragma unroll
                    for (int rr = 0; rr < 4; rr++) {
                        float p = exp2f(c[qq * 4 + rr] - m[g]);
                        if (rr & 1) rs1 += p; else rs0 += p;
                        pfrag[g][sub * 4 + qq][rr] = (_Float16)p;
                    }
                }
                lsum[g] += rs0 + rs1;
            }
        }

        // O[d][q] += V * P  (V LDS reads shared by both q-groups)
        #pragma unroll
        for (int slot = 0; slot < 8; slot++) {
            #pragma unroll
            for (int dt = 0; dt < 4; dt++) {
                int kc2 = (slot + dt * 4 + (L >> 3)) & 7;
                f16x4 av = *(const f16x4*)(&Vs[cur][(dt * 32 + L) * 72 + kc2 * 8 + hl * 4]);
                o_acc[0][dt] = __builtin_amdgcn_mfma_f32_32x32x8f16(av, pfrag[0][slot], o_acc[0][dt], 0, 0, 0);
                o_acc[1][dt] = __builtin_amdgcn_mfma_f32_32x32x8f16(av, pfrag[1][slot], o_acc[1][dt], 0, 0, 0);
            }
        }

        // commit prefetched V into the other buffer; 1 barrier/iter
        if (kt < 15) {
            #pragma unroll
            for (int p = 0; p < 2; p++) {
                int g2 = t + p * 512, d = g2 >> 3, kc = g2 & 7;
                int kc2 = (kc + (d >> 3)) & 7;
                *(uint4*)(&Vs[cur ^ 1][d * 72 + kc2 * 8]) = (p == 0) ? vx0 : vx1;
            }
        }
        __syncthreads();
    }

    lsum[0] += __shfl_xor(lsum[0], 32, 64);
    lsum[1] += __shfl_xor(lsum[1], 32, 64);

    // epilogue: normalize, split hi/lo, store xxT[b][n=q][d]
    #pragma unroll
    for (int g = 0; g < 2; g++) {
        float rl = 1.f / lsum[g];
        int q = qt * 512 + w * 64 + g * 32 + L;
        #pragma unroll
        for (int dt = 0; dt < 4; dt++) {
            #pragma unroll
            for (int gg = 0; gg < 4; gg++) {
                f16x4 hv, lv;
                #pragma unroll
                for (int rr = 0; rr < 4; rr++) {
                    float v = o_acc[g][dt][gg * 4 + rr] * rl;
                    _Float16 hh = (_Float16)v;
                    hv[rr] = hh; lv[rr] = (_Float16)(v - (float)hh);
                }
                size_t o = ((size_t)(b * 1024) + q) * 1024 + h * 128 + dt * 32 + gg * 8 + hl * 4;
                *(f16x4*)(xxT_h + o) = hv;
                *(f16x4*)(xxT_l + o) = lv;
            }
        }
    }
}

// ---------------------------------------------------------------- gemm_out
// out[o][n] = (sum_c Wp[o,c]*xx[c,n]) * s + t, 2-term hi/lo on xx. fp32 out.
__global__ __launch_bounds__(256, 2) void gemm_out(
    const _Float16* __restrict__ wp_h,
    const _Float16* __restrict__ xxT_h, const _Float16* __restrict__ xxT_l,
    const float* __restrict__ S, const float* __restrict__ T,
    float* __restrict__ out)
{
    __shared__ __align__(16) _Float16 As[128 * 40];
    __shared__ __align__(16) _Float16 Bh[64 * 40];
    __shared__ __align__(16) _Float16 Bl[64 * 40];
    const int t = threadIdx.x, lane = t & 63, w = t >> 6;
    const int wr = w >> 1, wc = w & 1, l16 = lane & 15, lq = lane >> 4;
    const int o0 = blockIdx.x * 128, n0 = blockIdx.y * 64, b = blockIdx.z;

    f32x4 acc[4][2] = {};

    for (int kb = 0; kb < 1024; kb += 32) {
        __syncthreads();
        #pragma unroll
        for (int p = 0; p < 2; p++) {
            int g = t + p * 256, row = g >> 2, ch = g & 3;
            *(uint4*)(&As[row * 40 + ch * 8]) =
                *(const uint4*)(wp_h + (size_t)(o0 + row) * 1024 + kb + ch * 8);
        }
        {
            int row = t >> 2, ch = t & 3;
            size_t src = ((size_t)(b * 1024) + n0 + row) * 1024 + kb + ch * 8;
            *(uint4*)(&Bh[row * 40 + ch * 8]) = *(const uint4*)(xxT_h + src);
            *(uint4*)(&Bl[row * 40 + ch * 8]) = *(const uint4*)(xxT_l + src);
        }
        __syncthreads();

        f16x8 a[4], bh[2], bl[2];
        #pragma unroll
        for (int i = 0; i < 4; i++) a[i] = *(const f16x8*)(&As[(wr * 64 + i * 16 + l16) * 40 + lq * 8]);
        #pragma unroll
        for (int j = 0; j < 2; j++) {
            bh[j] = *(const f16x8*)(&Bh[(wc * 32 + j * 16 + l16) * 40 + lq * 8]);
            bl[j] = *(const f16x8*)(&Bl[(wc * 32 + j * 16 + l16) * 40 + lq * 8]);
        }
        #pragma unroll
        for (int i = 0; i < 4; i++)
            #pragma unroll
            for (int j = 0; j < 2; j++) {
                acc[i][j] = __builtin_amdgcn_mfma_f32_16x16x32_f16(a[i], bh[j], acc[i][j], 0, 0, 0);
                acc[i][j] = __builtin_amdgcn_mfma_f32_16x16x32_f16(a[i], bl[j], acc[i][j], 0, 0, 0);
            }
    }

    #pragma unroll
    for (int i = 0; i < 4; i++) {
        #pragma unroll
        for (int r = 0; r < 4; r++) {
            int o = o0 + wr * 64 + i * 16 + lq * 4 + r;
            float sc = S[o], sh = T[o];
            #pragma unroll
            for (int j = 0; j < 2; j++) {
                int n = n0 + wc * 32 + j * 16 + l16;
                out[((size_t)(b * 384) + o) * 1024 + n] = acc[i][j][r] * sc + sh;
            }
        }
    }
}

// ---------------------------------------------------------------- launch

extern "C" void kernel_launch(void* const* d_in, const int* in_sizes, int n_in,
                              void* d_out, int out_size, void* d_ws, size_t ws_size,
                              hipStream_t stream) {
    const float* x   = (const float*)d_in[0];
    const float* wq  = (const float*)d_in[1];
    const float* bnq = (const float*)d_in[2];
    const float* wk  = (const float*)d_in[3];
    const float* bnk = (const float*)d_in[4];
    const float* wv  = (const float*)d_in[5];
    const float* bnv = (const float*)d_in[6];
    const float* wp  = (const float*)d_in[7];
    const float* bnp = (const float*)d_in[8];
    float* out = (float*)d_out;
    (void)in_sizes; (void)n_in; (void)out_size; (void)ws_size;

    char* ws = (char*)d_ws;
    size_t off = 0;
    auto alloc = [&](size_t bytes) {
        void* p = ws + off;
        off = (off + bytes + 255) & ~(size_t)255;
        return p;
    };
    // --- region A: dead after gemm_qkv; reused as xxT_h (needs >= 33.56 MB) ---
    _Float16* xT_hi = (_Float16*)alloc((size_t)16 * 1024 * 384 * 2);   // 12.58 MB
    _Float16* xT_lo = (_Float16*)alloc((size_t)16 * 1024 * 384 * 2);   // 12.58 MB
    _Float16* wqk_h = (_Float16*)alloc((size_t)512 * 384 * 2);
    _Float16* wqk_l = (_Float16*)alloc((size_t)512 * 384 * 2);
    _Float16* wv_h  = (_Float16*)alloc((size_t)1024 * 384 * 2);
    alloc((size_t)7 * 1024 * 1024);                                     // pad region A to > 33.56 MB
    _Float16* xxT_h = (_Float16*)d_ws;                                  // alias over region A
    // --- live buffers ---
    _Float16* wp_h  = (_Float16*)alloc((size_t)384 * 1024 * 2);
    float*    s_qkv = (float*)alloc(1536 * 4);
    float*    t_qkv = (float*)alloc(1536 * 4);
    float*    s_p   = (float*)alloc(384 * 4);
    float*    t_p   = (float*)alloc(384 * 4);
    _Float16* qT_h  = (_Float16*)alloc((size_t)16 * 8 * 1024 * 32 * 2); // 8.39 MB
    _Float16* qT_l  = (_Float16*)alloc((size_t)16 * 8 * 1024 * 32 * 2); // 8.39 MB
    _Float16* kT_h  = (_Float16*)alloc((size_t)16 * 8 * 1024 * 32 * 2); // 8.39 MB
    _Float16* kT_l  = (_Float16*)alloc((size_t)16 * 8 * 1024 * 32 * 2); // 8.39 MB
    _Float16* vbuf  = (_Float16*)alloc((size_t)16 * 1024 * 1024 * 2);   // 33.55 MB
    _Float16* xxT_l = (_Float16*)alloc((size_t)16 * 1024 * 1024 * 2);   // 33.55 MB

    prep<<<dim3(6, 16, 17), dim3(256), 0, stream>>>(
        x, wq, wk, wv, wp, bnq, bnk, bnv, bnp,
        xT_hi, xT_lo, wqk_h, wqk_l, wv_h, wp_h, s_qkv, t_qkv, s_p, t_p);

    gemm_qkv<<<dim3(12, 8, 16), dim3(256), 0, stream>>>(
        wqk_h, wqk_l, wv_h, xT_hi, xT_lo, s_qkv, t_qkv,
        qT_h, qT_l, kT_h, kT_l, vbuf);

    attn<<<dim3(128, 2), dim3(512), 0, stream>>>(qT_h, qT_l, kT_h, kT_l, vbuf, xxT_h, xxT_l);

    gemm_out<<<dim3(3, 16, 16), dim3(256), 0, stream>>>(wp_h, xxT_h, xxT_l, s_p, t_p, out);
}

// Round 6
// 327.868 us; speedup vs baseline: 1.3067x; 1.3067x over previous
//
#include <hip/hip_runtime.h>

typedef _Float16 f16x8 __attribute__((ext_vector_type(8)));
typedef _Float16 f16x4 __attribute__((ext_vector_type(4)));
typedef float f32x4 __attribute__((ext_vector_type(4)));
typedef float f32x16 __attribute__((ext_vector_type(16)));

#define BN_EPS 1e-5f
#define SQRT32 5.656854249492381f
#define LOG2E  1.4426950408889634f

typedef const __attribute__((address_space(1))) void* gas_p;
typedef __attribute__((address_space(3))) void* las_p;

// ---------------------------------------------------------------- prep (merged)
// z<16: x [b][c=384][n] fp32 -> xT_hi/lo [b][n][c] fp16 planes (transpose+split).
// z==16: weight conversion + BN affine fold.
__global__ __launch_bounds__(256) void prep(
    const float* __restrict__ x,
    const float* __restrict__ wq, const float* __restrict__ wk,
    const float* __restrict__ wv, const float* __restrict__ wp,
    const float* __restrict__ bnq, const float* __restrict__ bnk,
    const float* __restrict__ bnv, const float* __restrict__ bnp,
    _Float16* __restrict__ xT_hi, _Float16* __restrict__ xT_lo,
    _Float16* __restrict__ wqk_h, _Float16* __restrict__ wqk_l,
    _Float16* __restrict__ wv_h,  _Float16* __restrict__ wp_h,
    float* __restrict__ s_qkv, float* __restrict__ t_qkv,
    float* __restrict__ s_p,   float* __restrict__ t_p)
{
    __shared__ float Tx[64][65];
    const int t = threadIdx.x;
    if (blockIdx.z < 16) {
        const int ct = blockIdx.x, nt = blockIdx.y, b = blockIdx.z;
        const int c0 = ct * 64, n0 = nt * 64;
        {
            int tr = t >> 4, tc = (t & 15) * 4;
            #pragma unroll
            for (int p = 0; p < 4; p++) {
                int r = tr + p * 16;
                float4 v = *(const float4*)(x + ((size_t)(b * 384 + c0 + r)) * 1024 + n0 + tc);
                Tx[r][tc + 0] = v.x; Tx[r][tc + 1] = v.y; Tx[r][tc + 2] = v.z; Tx[r][tc + 3] = v.w;
            }
        }
        __syncthreads();
        {
            int nn = t >> 2, cc = (t & 3) * 16;
            f16x8 h0, h1, l0, l1;
            #pragma unroll
            for (int i = 0; i < 8; i++) {
                float v = Tx[cc + i][nn];
                _Float16 hh = (_Float16)v;
                h0[i] = hh; l0[i] = (_Float16)(v - (float)hh);
            }
            #pragma unroll
            for (int i = 0; i < 8; i++) {
                float v = Tx[cc + 8 + i][nn];
                _Float16 hh = (_Float16)v;
                h1[i] = hh; l1[i] = (_Float16)(v - (float)hh);
            }
            size_t o = ((size_t)(b * 1024 + n0 + nn)) * 384 + c0 + cc;
            *(f16x8*)(xT_hi + o) = h0; *(f16x8*)(xT_hi + o + 8) = h1;
            *(f16x8*)(xT_lo + o) = l0; *(f16x8*)(xT_lo + o + 8) = l1;
        }
    } else {
        const int NQK = 512 * 384, NV = 1024 * 384, NP = 384 * 1024;
        int tid = (blockIdx.y * 6 + blockIdx.x) * 256 + t;       // 0..24575
        for (int i = tid; i < NQK + NV + NP; i += 24576) {
            if (i < NQK) {
                int o = i / 384, c = i - o * 384;
                float v = (o < 256) ? wq[o * 384 + c] : wk[(o - 256) * 384 + c];
                _Float16 hh = (_Float16)v;
                wqk_h[i] = hh; wqk_l[i] = (_Float16)(v - (float)hh);
            } else if (i < NQK + NV) {
                wv_h[i - NQK] = (_Float16)wv[i - NQK];
            } else {
                wp_h[i - NQK - NV] = (_Float16)wp[i - NQK - NV];
            }
        }
        if (tid < 1536) {
            int i = tid;
            float g, be, m, v;
            if (i < 256)      { int o = i;       g = bnq[o]; be = bnq[256 + o];  m = bnq[512 + o];  v = bnq[768 + o]; }
            else if (i < 512) { int o = i - 256; g = bnk[o]; be = bnk[256 + o];  m = bnk[512 + o];  v = bnk[768 + o]; }
            else              { int o = i - 512; g = bnv[o]; be = bnv[1024 + o]; m = bnv[2048 + o]; v = bnv[3072 + o]; }
            float s = g * rsqrtf(v + BN_EPS);
            float tt = be - m * s;
            // fold /scale (= *sqrt(kd)) AND log2(e) (exp2 softmax) into Q's affine
            if (i < 256) { s *= SQRT32 * LOG2E; tt *= SQRT32 * LOG2E; }
            s_qkv[i] = s; t_qkv[i] = tt;
        } else if (tid < 1536 + 384) {
            int o = tid - 1536;
            float g = bnp[o], be = bnp[384 + o], m = bnp[768 + o], v = bnp[1152 + o];
            float s = g * rsqrtf(v + BN_EPS);
            s_p[o] = s; t_p[o] = be - m * s;
        }
    }
}

// ---------------------------------------------------------------- gemm_qkv
// bx<4 (Q/K rows): computes D[n][o] (transposed, 3-term hi/lo) and writes
// qT/kT [b][h][n][32] hi/lo fp16 planes directly.
// bx>=4 (V rows): D[o][n] 1-term, fp16 out, natural layout.
__global__ __launch_bounds__(256, 2) void gemm_qkv(
    const _Float16* __restrict__ wqk_h, const _Float16* __restrict__ wqk_l,
    const _Float16* __restrict__ wv_h,
    const _Float16* __restrict__ xT_hi, const _Float16* __restrict__ xT_lo,
    const float* __restrict__ S, const float* __restrict__ T,
    _Float16* __restrict__ qT_h, _Float16* __restrict__ qT_l,
    _Float16* __restrict__ kT_h, _Float16* __restrict__ kT_l,
    _Float16* __restrict__ vbuf)
{
    __shared__ __align__(16) _Float16 As_h[128 * 40];
    __shared__ __align__(16) _Float16 As_l[128 * 40];
    __shared__ __align__(16) _Float16 Bs_h[128 * 40];
    __shared__ __align__(16) _Float16 Bs_l[128 * 40];
    const int t = threadIdx.x, lane = t & 63, w = t >> 6;
    const int wr = w >> 1, wc = w & 1, l16 = lane & 15, lq = lane >> 4;
    const int bx = blockIdx.x, n0 = blockIdx.y * 128, b = blockIdx.z;
    const bool isv = bx >= 4;
    const int o0 = isv ? (bx - 4) * 128 : bx * 128;
    const _Float16* __restrict__ Ah = isv ? wv_h : wqk_h;

    f32x4 acc[4][4] = {};

    for (int kb = 0; kb < 384; kb += 32) {
        __syncthreads();
        #pragma unroll
        for (int p = 0; p < 2; p++) {
            int g = t + p * 256, row = g >> 2, ch = g & 3;
            *(uint4*)(&As_h[row * 40 + ch * 8]) =
                *(const uint4*)(Ah + (size_t)(o0 + row) * 384 + kb + ch * 8);
        }
        #pragma unroll
        for (int p = 0; p < 2; p++) {
            int g = t + p * 256, row = g >> 2, ch = g & 3;
            *(uint4*)(&Bs_h[row * 40 + ch * 8]) =
                *(const uint4*)(xT_hi + ((size_t)(b * 1024) + n0 + row) * 384 + kb + ch * 8);
        }
        if (!isv) {
            #pragma unroll
            for (int p = 0; p < 2; p++) {
                int g = t + p * 256, row = g >> 2, ch = g & 3;
                *(uint4*)(&As_l[row * 40 + ch * 8]) =
                    *(const uint4*)(wqk_l + (size_t)(o0 + row) * 384 + kb + ch * 8);
            }
            #pragma unroll
            for (int p = 0; p < 2; p++) {
                int g = t + p * 256, row = g >> 2, ch = g & 3;
                *(uint4*)(&Bs_l[row * 40 + ch * 8]) =
                    *(const uint4*)(xT_lo + ((size_t)(b * 1024) + n0 + row) * 384 + kb + ch * 8);
            }
        }
        __syncthreads();

        if (!isv) {
            // transposed: A = x tiles (n rows), B = w tiles (o cols)
            f16x8 ah[4], al[4], bh[4], bl[4];
            #pragma unroll
            for (int i = 0; i < 4; i++) {
                ah[i] = *(const f16x8*)(&Bs_h[(wr * 64 + i * 16 + l16) * 40 + lq * 8]);
                al[i] = *(const f16x8*)(&Bs_l[(wr * 64 + i * 16 + l16) * 40 + lq * 8]);
            }
            #pragma unroll
            for (int j = 0; j < 4; j++) {
                bh[j] = *(const f16x8*)(&As_h[(wc * 64 + j * 16 + l16) * 40 + lq * 8]);
                bl[j] = *(const f16x8*)(&As_l[(wc * 64 + j * 16 + l16) * 40 + lq * 8]);
            }
            #pragma unroll
            for (int i = 0; i < 4; i++)
                #pragma unroll
                for (int j = 0; j < 4; j++) {
                    acc[i][j] = __builtin_amdgcn_mfma_f32_16x16x32_f16(ah[i], bh[j], acc[i][j], 0, 0, 0);
                    acc[i][j] = __builtin_amdgcn_mfma_f32_16x16x32_f16(al[i], bh[j], acc[i][j], 0, 0, 0);
                    acc[i][j] = __builtin_amdgcn_mfma_f32_16x16x32_f16(ah[i], bl[j], acc[i][j], 0, 0, 0);
                }
        } else {
            f16x8 a[4], bf[4];
            #pragma unroll
            for (int i = 0; i < 4; i++) a[i]  = *(const f16x8*)(&As_h[(wr * 64 + i * 16 + l16) * 40 + lq * 8]);
            #pragma unroll
            for (int j = 0; j < 4; j++) bf[j] = *(const f16x8*)(&Bs_h[(wc * 64 + j * 16 + l16) * 40 + lq * 8]);
            #pragma unroll
            for (int i = 0; i < 4; i++)
                #pragma unroll
                for (int j = 0; j < 4; j++)
                    acc[i][j] = __builtin_amdgcn_mfma_f32_16x16x32_f16(a[i], bf[j], acc[i][j], 0, 0, 0);
        }
    }

    if (!isv) {
        // D[n][o]: row = n, col(l16) = o. Write qT/kT hi/lo planes directly.
        #pragma unroll
        for (int i = 0; i < 4; i++) {
            #pragma unroll
            for (int r = 0; r < 4; r++) {
                int n = n0 + wr * 64 + i * 16 + lq * 4 + r;
                #pragma unroll
                for (int j = 0; j < 4; j++) {
                    int o = o0 + wc * 64 + j * 16 + l16;
                    float sc = S[o], sh = T[o];
                    float v = acc[i][j][r] * sc + sh;
                    _Float16 hh = (_Float16)v;
                    _Float16 ll = (_Float16)(v - (float)hh);
                    int oo = o & 255;
                    size_t idx = (((size_t)(b * 8) + (oo >> 5)) * 1024 + n) * 32 + (oo & 31);
                    if (o < 256) { qT_h[idx] = hh; qT_l[idx] = ll; }
                    else         { kT_h[idx] = hh; kT_l[idx] = ll; }
                }
            }
        }
    } else {
        #pragma unroll
        for (int i = 0; i < 4; i++) {
            #pragma unroll
            for (int r = 0; r < 4; r++) {
                int o = o0 + wr * 64 + i * 16 + lq * 4 + r;
                float sc = S[512 + o], sh = T[512 + o];
                #pragma unroll
                for (int j = 0; j < 4; j++) {
                    int n = n0 + wc * 64 + j * 16 + l16;
                    vbuf[((size_t)(b * 1024) + o) * 1024 + n] = (_Float16)(acc[i][j][r] * sc + sh);
                }
            }
        }
    }
}

// ---------------------------------------------------------------- attn
// Online-softmax flash attention (round-4 numerics). 256 thr = 4 waves,
// 256 q/block, grid (bh=128, qt=4) = 512 blocks = 2/CU (two independent
// barrier domains per CU -> inter-block latency hiding at the fixed
// 2-waves/SIMD register occupancy).
// V tile: async global->LDS DMA (global_load_lds, 16B), double-buffered,
// XOR column swizzle (kc_lds = kc ^ (d&7)) for lane-contiguous DMA + 4-way-max
// read conflicts. K: per-lane global loads issued BEFORE the DMA so their
// vmcnt wait does not drain the DMA queue. Rescale of o_acc gated by
// __any(max-changed) -- skipped on ~13/16 tiles.
__device__ __forceinline__ f32x16 qk6(f16x8 kh0, f16x8 kl0, f16x8 kh1, f16x8 kl1,
                                      f16x8 qh0, f16x8 ql0, f16x8 qh1, f16x8 ql1) {
    f32x16 c = {};
    c = __builtin_amdgcn_mfma_f32_32x32x16_f16(kh0, qh0, c, 0, 0, 0);
    c = __builtin_amdgcn_mfma_f32_32x32x16_f16(kl0, qh0, c, 0, 0, 0);
    c = __builtin_amdgcn_mfma_f32_32x32x16_f16(kh0, ql0, c, 0, 0, 0);
    c = __builtin_amdgcn_mfma_f32_32x32x16_f16(kh1, qh1, c, 0, 0, 0);
    c = __builtin_amdgcn_mfma_f32_32x32x16_f16(kl1, qh1, c, 0, 0, 0);
    c = __builtin_amdgcn_mfma_f32_32x32x16_f16(kh1, ql1, c, 0, 0, 0);
    return c;
}

__global__ __launch_bounds__(256, 2) void attn(
    const _Float16* __restrict__ qT_h, const _Float16* __restrict__ qT_l,
    const _Float16* __restrict__ kT_h, const _Float16* __restrict__ kT_l,
    const _Float16* __restrict__ vbuf,
    _Float16* __restrict__ xxT_h, _Float16* __restrict__ xxT_l)
{
    __shared__ __align__(16) _Float16 Vs[2][128 * 64];
    const int t = threadIdx.x, lane = t & 63, w = t >> 6;
    const int L = lane & 31, hl = lane >> 5;
    const int bh = blockIdx.x, qt = blockIdx.y;
    const int b = bh >> 3, h = bh & 7;
    const size_t vbase = ((size_t)(b * 1024) + h * 128) * 1024;

    // Q B-frags (hi/lo planes, direct f16 loads)
    f16x8 bq_h[2][2], bq_l[2][2];
    #pragma unroll
    for (int g = 0; g < 2; g++) {
        int q = qt * 256 + w * 64 + g * 32 + L;
        #pragma unroll
        for (int kh = 0; kh < 2; kh++) {
            size_t base = ((size_t)(bh * 1024) + q) * 32 + kh * 16 + hl * 8;
            bq_h[g][kh] = *(const f16x8*)(qT_h + base);
            bq_l[g][kh] = *(const f16x8*)(qT_l + base);
        }
    }

    f32x16 o_acc[2][4] = {};
    float m_st[2] = {-INFINITY, -INFINITY}, l_st[2] = {0.f, 0.f};

    // async DMA of V tile kt into Vs[buf]; lane-contiguous LDS dest,
    // per-lane global src with XOR column swizzle.
    #define DMA_TILE(buf, kt_)                                                     \
        {                                                                          \
            _Pragma("unroll")                                                      \
            for (int p = 0; p < 4; p++) {                                          \
                int g2 = t + p * 256;                                              \
                int d = g2 >> 3;                                                   \
                int kcg = (g2 & 7) ^ (d & 7);                                      \
                const _Float16* src = vbuf + vbase + (size_t)d * 1024              \
                                      + (kt_) * 64 + kcg * 8;                      \
                _Float16* dst = &Vs[buf][(p * 256 + w * 64) * 8];                  \
                __builtin_amdgcn_global_load_lds((gas_p)(const void*)src,          \
                                                 (las_p)(void*)dst, 16, 0, 0);     \
            }                                                                      \
        }

    DMA_TILE(0, 0)
    __syncthreads();

    for (int kt = 0; kt < 16; kt++) {
        const int cur = kt & 1;

        // K loads for the whole iteration FIRST (so vmcnt waits for K leave
        // the later DMA in flight)
        f16x8 K0h, K0l, K1h, K1l, K2h, K2l, K3h, K3l;
        {
            size_t kb0 = ((size_t)(bh * 1024) + kt * 64 + L) * 32 + hl * 8;      // sub 0
            size_t kb1 = kb0 + 32 * 32;                                           // sub 1
            K0h = *(const f16x8*)(kT_h + kb0);      K0l = *(const f16x8*)(kT_l + kb0);
            K1h = *(const f16x8*)(kT_h + kb0 + 16); K1l = *(const f16x8*)(kT_l + kb0 + 16);
            K2h = *(const f16x8*)(kT_h + kb1);      K2l = *(const f16x8*)(kT_l + kb1);
            K3h = *(const f16x8*)(kT_h + kb1 + 16); K3l = *(const f16x8*)(kT_l + kb1 + 16);
        }
        if (kt < 15) DMA_TILE(cur ^ 1, kt + 1)

        f16x4 pfrag[2][8];
        #pragma unroll
        for (int g = 0; g < 2; g++) {
            f32x16 c0 = qk6(K0h, K0l, K1h, K1l, bq_h[g][0], bq_l[g][0], bq_h[g][1], bq_l[g][1]);
            f32x16 c1 = qk6(K2h, K2l, K3h, K3l, bq_h[g][0], bq_l[g][0], bq_h[g][1], bq_l[g][1]);
            float mx = -INFINITY;
            #pragma unroll
            for (int i = 0; i < 16; i++) mx = fmaxf(mx, fmaxf(c0[i], c1[i]));
            mx = fmaxf(mx, __shfl_xor(mx, 32, 64));
            float mnew = fmaxf(m_st[g], mx);
            if (__any(mnew > m_st[g])) {                  // wave-uniform skip
                float a = exp2f(m_st[g] - mnew);
                l_st[g] *= a;
                #pragma unroll
                for (int dt = 0; dt < 4; dt++)
                    #pragma unroll
                    for (int i = 0; i < 16; i++) o_acc[g][dt][i] *= a;
            }
            m_st[g] = mnew;
            float rs = 0.f;
            #pragma unroll
            for (int qq = 0; qq < 4; qq++)
                #pragma unroll
                for (int rr = 0; rr < 4; rr++) {
                    float p0 = exp2f(c0[qq * 4 + rr] - mnew);
                    float p1 = exp2f(c1[qq * 4 + rr] - mnew);
                    rs += p0 + p1;
                    pfrag[g][qq][rr] = (_Float16)p0;
                    pfrag[g][4 + qq][rr] = (_Float16)p1;
                }
            l_st[g] += rs;          // per-lane partial; combined across hl at end
        }

        // O[d][q] += V * P  (V LDS reads shared by both q-groups)
        #pragma unroll
        for (int slot = 0; slot < 8; slot++) {
            int col = slot ^ (L & 7);
            #pragma unroll
            for (int dt = 0; dt < 4; dt++) {
                f16x4 av = *(const f16x4*)(&Vs[cur][(dt * 32 + L) * 64 + col * 8 + hl * 4]);
                o_acc[0][dt] = __builtin_amdgcn_mfma_f32_32x32x8f16(av, pfrag[0][slot], o_acc[0][dt], 0, 0, 0);
                o_acc[1][dt] = __builtin_amdgcn_mfma_f32_32x32x8f16(av, pfrag[1][slot], o_acc[1][dt], 0, 0, 0);
            }
        }

        if (kt < 15) __syncthreads();   // drains this iter's DMA + joins waves
    }
    #undef DMA_TILE

    l_st[0] += __shfl_xor(l_st[0], 32, 64);
    l_st[1] += __shfl_xor(l_st[1], 32, 64);

    // epilogue: normalize, split hi/lo, store xxT[b][n=q][d]
    #pragma unroll
    for (int g = 0; g < 2; g++) {
        float rl = 1.f / l_st[g];
        int q = qt * 256 + w * 64 + g * 32 + L;
        #pragma unroll
        for (int dt = 0; dt < 4; dt++) {
            #pragma unroll
            for (int gg = 0; gg < 4; gg++) {
                f16x4 hv, lv;
                #pragma unroll
                for (int rr = 0; rr < 4; rr++) {
                    float v = o_acc[g][dt][gg * 4 + rr] * rl;
                    _Float16 hh = (_Float16)v;
                    hv[rr] = hh; lv[rr] = (_Float16)(v - (float)hh);
                }
                size_t o = ((size_t)(b * 1024) + q) * 1024 + h * 128 + dt * 32 + gg * 8 + hl * 4;
                *(f16x4*)(xxT_h + o) = hv;
                *(f16x4*)(xxT_l + o) = lv;
            }
        }
    }
}

// ---------------------------------------------------------------- gemm_out
// out[o][n] = (sum_c Wp[o,c]*xx[c,n]) * s + t, 2-term hi/lo on xx. fp32 out.
__global__ __launch_bounds__(256, 2) void gemm_out(
    const _Float16* __restrict__ wp_h,
    const _Float16* __restrict__ xxT_h, const _Float16* __restrict__ xxT_l,
    const float* __restrict__ S, const float* __restrict__ T,
    float* __restrict__ out)
{
    __shared__ __align__(16) _Float16 As[128 * 40];
    __shared__ __align__(16) _Float16 Bh[64 * 40];
    __shared__ __align__(16) _Float16 Bl[64 * 40];
    const int t = threadIdx.x, lane = t & 63, w = t >> 6;
    const int wr = w >> 1, wc = w & 1, l16 = lane & 15, lq = lane >> 4;
    const int o0 = blockIdx.x * 128, n0 = blockIdx.y * 64, b = blockIdx.z;

    f32x4 acc[4][2] = {};

    for (int kb = 0; kb < 1024; kb += 32) {
        __syncthreads();
        #pragma unroll
        for (int p = 0; p < 2; p++) {
            int g = t + p * 256, row = g >> 2, ch = g & 3;
            *(uint4*)(&As[row * 40 + ch * 8]) =
                *(const uint4*)(wp_h + (size_t)(o0 + row) * 1024 + kb + ch * 8);
        }
        {
            int row = t >> 2, ch = t & 3;
            size_t src = ((size_t)(b * 1024) + n0 + row) * 1024 + kb + ch * 8;
            *(uint4*)(&Bh[row * 40 + ch * 8]) = *(const uint4*)(xxT_h + src);
            *(uint4*)(&Bl[row * 40 + ch * 8]) = *(const uint4*)(xxT_l + src);
        }
        __syncthreads();

        f16x8 a[4], bh[2], bl[2];
        #pragma unroll
        for (int i = 0; i < 4; i++) a[i] = *(const f16x8*)(&As[(wr * 64 + i * 16 + l16) * 40 + lq * 8]);
        #pragma unroll
        for (int j = 0; j < 2; j++) {
            bh[j] = *(const f16x8*)(&Bh[(wc * 32 + j * 16 + l16) * 40 + lq * 8]);
            bl[j] = *(const f16x8*)(&Bl[(wc * 32 + j * 16 + l16) * 40 + lq * 8]);
        }
        #pragma unroll
        for (int i = 0; i < 4; i++)
            #pragma unroll
            for (int j = 0; j < 2; j++) {
                acc[i][j] = __builtin_amdgcn_mfma_f32_16x16x32_f16(a[i], bh[j], acc[i][j], 0, 0, 0);
                acc[i][j] = __builtin_amdgcn_mfma_f32_16x16x32_f16(a[i], bl[j], acc[i][j], 0, 0, 0);
            }
    }

    #pragma unroll
    for (int i = 0; i < 4; i++) {
        #pragma unroll
        for (int r = 0; r < 4; r++) {
            int o = o0 + wr * 64 + i * 16 + lq * 4 + r;
            float sc = S[o], sh = T[o];
            #pragma unroll
            for (int j = 0; j < 2; j++) {
                int n = n0 + wc * 32 + j * 16 + l16;
                out[((size_t)(b * 384) + o) * 1024 + n] = acc[i][j][r] * sc + sh;
            }
        }
    }
}

// ---------------------------------------------------------------- launch

extern "C" void kernel_launch(void* const* d_in, const int* in_sizes, int n_in,
                              void* d_out, int out_size, void* d_ws, size_t ws_size,
                              hipStream_t stream) {
    const float* x   = (const float*)d_in[0];
    const float* wq  = (const float*)d_in[1];
    const float* bnq = (const float*)d_in[2];
    const float* wk  = (const float*)d_in[3];
    const float* bnk = (const float*)d_in[4];
    const float* wv  = (const float*)d_in[5];
    const float* bnv = (const float*)d_in[6];
    const float* wp  = (const float*)d_in[7];
    const float* bnp = (const float*)d_in[8];
    float* out = (float*)d_out;
    (void)in_sizes; (void)n_in; (void)out_size; (void)ws_size;

    char* ws = (char*)d_ws;
    size_t off = 0;
    auto alloc = [&](size_t bytes) {
        void* p = ws + off;
        off = (off + bytes + 255) & ~(size_t)255;
        return p;
    };
    // --- region A: dead after gemm_qkv; reused as xxT_h (needs >= 33.56 MB) ---
    _Float16* xT_hi = (_Float16*)alloc((size_t)16 * 1024 * 384 * 2);   // 12.58 MB
    _Float16* xT_lo = (_Float16*)alloc((size_t)16 * 1024 * 384 * 2);   // 12.58 MB
    _Float16* wqk_h = (_Float16*)alloc((size_t)512 * 384 * 2);
    _Float16* wqk_l = (_Float16*)alloc((size_t)512 * 384 * 2);
    _Float16* wv_h  = (_Float16*)alloc((size_t)1024 * 384 * 2);
    alloc((size_t)7 * 1024 * 1024);                                     // pad region A to > 33.56 MB
    _Float16* xxT_h = (_Float16*)d_ws;                                  // alias over region A
    // --- live buffers ---
    _Float16* wp_h  = (_Float16*)alloc((size_t)384 * 1024 * 2);
    float*    s_qkv = (float*)alloc(1536 * 4);
    float*    t_qkv = (float*)alloc(1536 * 4);
    float*    s_p   = (float*)alloc(384 * 4);
    float*    t_p   = (float*)alloc(384 * 4);
    _Float16* qT_h  = (_Float16*)alloc((size_t)16 * 8 * 1024 * 32 * 2); // 8.39 MB
    _Float16* qT_l  = (_Float16*)alloc((size_t)16 * 8 * 1024 * 32 * 2); // 8.39 MB
    _Float16* kT_h  = (_Float16*)alloc((size_t)16 * 8 * 1024 * 32 * 2); // 8.39 MB
    _Float16* kT_l  = (_Float16*)alloc((size_t)16 * 8 * 1024 * 32 * 2); // 8.39 MB
    _Float16* vbuf  = (_Float16*)alloc((size_t)16 * 1024 * 1024 * 2);   // 33.55 MB
    _Float16* xxT_l = (_Float16*)alloc((size_t)16 * 1024 * 1024 * 2);   // 33.55 MB

    prep<<<dim3(6, 16, 17), dim3(256), 0, stream>>>(
        x, wq, wk, wv, wp, bnq, bnk, bnv, bnp,
        xT_hi, xT_lo, wqk_h, wqk_l, wv_h, wp_h, s_qkv, t_qkv, s_p, t_p);

    gemm_qkv<<<dim3(12, 8, 16), dim3(256), 0, stream>>>(
        wqk_h, wqk_l, wv_h, xT_hi, xT_lo, s_qkv, t_qkv,
        qT_h, qT_l, kT_h, kT_l, vbuf);

    attn<<<dim3(128, 4), dim3(256), 0, stream>>>(qT_h, qT_l, kT_h, kT_l, vbuf, xxT_h, xxT_l);

    gemm_out<<<dim3(3, 16, 16), dim3(256), 0, stream>>>(wp_h, xxT_h, xxT_l, s_p, t_p, out);
}